// Round 7
// baseline (165.617 us; speedup 1.0000x reference)
//
#include <hip/hip_runtime.h>
#include <hip/hip_bf16.h>
#include <math.h>

#define CHUNK 1024

typedef __attribute__((ext_vector_type(8))) short bf16x8;
typedef __attribute__((ext_vector_type(4))) float f32x4;

__device__ __forceinline__ unsigned short f2bf(float f) {
    unsigned u = __float_as_uint(f);
    unsigned r = ((u >> 16) & 1u) + 0x7fffu;   // RNE
    return (unsigned short)((u + r) >> 16);
}

// ---- prep: wsrc/wdst = W^T @ att halves (fp32, exact), + bias consts -------
// wsd layout: [0,512) wsrc[4][128]; [512,1024) wdst[4][128]; [1024,1032) cs[4],cd[4]
__global__ __launch_bounds__(256) void k_prep(const float* __restrict__ W,
                                              const float* __restrict__ bias,
                                              const float* __restrict__ att,
                                              float* __restrict__ wsd) {
    int t = threadIdx.x;
    if (t < 128) {
        int k = t;
#pragma unroll
        for (int hd = 0; hd < 4; ++hd) {
            float ss = 0.f, sd = 0.f;
            for (int j = 0; j < 32; ++j) {
                float w = W[(size_t)(hd * 32 + j) * 128 + k];
                ss += w * att[hd * 65 + j];
                sd += w * att[hd * 65 + 32 + j];
            }
            wsd[hd * 128 + k] = ss;
            wsd[512 + hd * 128 + k] = sd;
        }
    } else if (t < 136) {
        int hd = (t - 128) & 3;
        bool isD = (t - 128) >= 4;
        float c = 0.f;
        for (int j = 0; j < 32; ++j)
            c += bias[hd * 32 + j] * att[hd * 65 + (isD ? 32 + j : j)];
        wsd[1024 + (isD ? 4 : 0) + hd] = c;
    }
}

// ---- mega: MFMA GEMM (z=h@W^T+b, bf16 in / fp32 acc) + scores + hist -------
// gemm block: 64 nodes x 128 outs; LDS granule (kg, row) = 8 bf16 laid out as
// the mfma_f32_16x16x32_bf16 fragment: elems e: k = ks*32 + (e>>2)*16 + g*4 + (e&3)
// with kg = ks*4+g; rows XOR-swizzled by (kg&7) for conflict-free staging.
__global__ __launch_bounds__(256) void k_mega(
        const float* __restrict__ h, const float* __restrict__ W,
        const float* __restrict__ bias, const float* __restrict__ wsd,
        const int* __restrict__ dstI, int* __restrict__ counts,
        float* __restrict__ z, unsigned short* __restrict__ zb16,
        float* __restrict__ s_src, float* __restrict__ s_dst,
        int N, int E, int gemmBlocks, int scoreBlocks) {
    __shared__ short hS[16 * 64 * 8];    // 16 KB
    __shared__ short wS[16 * 128 * 8];   // 32 KB
    const int t = threadIdx.x;
    const int bid = blockIdx.x;

    if (bid >= gemmBlocks + scoreBlocks) {     // ---- histogram (4 edges/thr) ----
        int base = (bid - gemmBlocks - scoreBlocks) * 1024 + t;
#pragma unroll
        for (int q = 0; q < 4; ++q) {
            int e = base + q * 256;
            if (e < E) atomicAdd(&counts[dstI[e]], 1);
        }
        return;
    }
    if (bid >= gemmBlocks) {                   // ---- scores: 8 lanes/node ----
        int sid = (bid - gemmBlocks) * 256 + t;
        int node = sid >> 3, p = sid & 7;
        if (node >= N) return;
        const float* hp = h + (size_t)node * 128 + p * 16;
        float ss[4] = {0.f, 0.f, 0.f, 0.f}, sd[4] = {0.f, 0.f, 0.f, 0.f};
#pragma unroll
        for (int q = 0; q < 4; ++q) {
            float4 hv = *reinterpret_cast<const float4*>(hp + q * 4);
#pragma unroll
            for (int hd = 0; hd < 4; ++hd) {
                float4 a = *reinterpret_cast<const float4*>(&wsd[hd * 128 + p * 16 + q * 4]);
                float4 b = *reinterpret_cast<const float4*>(&wsd[512 + hd * 128 + p * 16 + q * 4]);
                ss[hd] += hv.x * a.x + hv.y * a.y + hv.z * a.z + hv.w * a.w;
                sd[hd] += hv.x * b.x + hv.y * b.y + hv.z * b.z + hv.w * b.w;
            }
        }
#pragma unroll
        for (int off = 1; off < 8; off <<= 1) {
#pragma unroll
            for (int hd = 0; hd < 4; ++hd) {
                ss[hd] += __shfl_xor(ss[hd], off);
                sd[hd] += __shfl_xor(sd[hd], off);
            }
        }
        if (p == 0) {
            float4 cs = *reinterpret_cast<const float4*>(&wsd[1024]);
            float4 cd = *reinterpret_cast<const float4*>(&wsd[1028]);
            *reinterpret_cast<float4*>(&s_src[(size_t)node * 4]) =
                make_float4(ss[0] + cs.x, ss[1] + cs.y, ss[2] + cs.z, ss[3] + cs.w);
            *reinterpret_cast<float4*>(&s_dst[(size_t)node * 4]) =
                make_float4(sd[0] + cd.x, sd[1] + cd.y, sd[2] + cd.z, sd[3] + cd.w);
        }
        return;
    }

    // ---- GEMM block ----
    const int n0 = bid * 64;
    // stage h tile (64 x 128 fp32 -> bf16 fragments)
#pragma unroll
    for (int q = 0; q < 8; ++q) {
        int f = q * 256 + t;
        int node = f >> 5;
        int k4 = (f & 31) * 4;
        int ks = k4 >> 5, rr = k4 & 31;
        int half = rr >> 4, g = (rr & 15) >> 2;
        int kg = ks * 4 + g;
        int slot = kg * 64 + (node ^ (kg & 7));
        int hn = n0 + node; if (hn > N - 1) hn = N - 1;
        float4 v = *reinterpret_cast<const float4*>(&h[(size_t)hn * 128 + k4]);
        uint2 pk = make_uint2(((unsigned)f2bf(v.y) << 16) | f2bf(v.x),
                              ((unsigned)f2bf(v.w) << 16) | f2bf(v.z));
        *reinterpret_cast<uint2*>(&hS[slot * 8 + half * 4]) = pk;
    }
    // stage W (128 x 128 fp32 -> bf16 fragments)
#pragma unroll
    for (int q = 0; q < 16; ++q) {
        int f = q * 256 + t;
        int row = f >> 5;
        int k4 = (f & 31) * 4;
        int ks = k4 >> 5, rr = k4 & 31;
        int half = rr >> 4, g = (rr & 15) >> 2;
        int kg = ks * 4 + g;
        int slot = kg * 128 + (row ^ (kg & 7));
        float4 v = *reinterpret_cast<const float4*>(&W[(size_t)row * 128 + k4]);
        uint2 pk = make_uint2(((unsigned)f2bf(v.y) << 16) | f2bf(v.x),
                              ((unsigned)f2bf(v.w) << 16) | f2bf(v.z));
        *reinterpret_cast<uint2*>(&wS[slot * 8 + half * 4]) = pk;
    }
    __syncthreads();

    const int wv = t >> 6, l = t & 63;
    const int la = l & 15, lb = l >> 4;
    const int nbase = wv * 16;

    bf16x8 afr[4];
#pragma unroll
    for (int ks = 0; ks < 4; ++ks) {
        int kg = ks * 4 + lb;
        int slot = kg * 64 + ((nbase + la) ^ (kg & 7));
        afr[ks] = *reinterpret_cast<const bf16x8*>(&hS[slot * 8]);
    }

#pragma unroll
    for (int ot = 0; ot < 8; ++ot) {
        f32x4 acc = {0.f, 0.f, 0.f, 0.f};
#pragma unroll
        for (int ks = 0; ks < 4; ++ks) {
            int kg = ks * 4 + lb;
            int slot = kg * 128 + ((ot * 16 + la) ^ (kg & 7));
            bf16x8 bfr = *reinterpret_cast<const bf16x8*>(&wS[slot * 8]);
            acc = __builtin_amdgcn_mfma_f32_16x16x32_bf16(afr[ks], bfr, acc, 0, 0, 0);
        }
        int col = ot * 16 + la;
        float bv = bias[col];
#pragma unroll
        for (int r = 0; r < 4; ++r) {
            int node = n0 + nbase + lb * 4 + r;
            if (node < N) {
                float v = acc[r] + bv;
                z[(size_t)node * 128 + col] = v;
                zb16[(size_t)node * 128 + col] = f2bf(v);
            }
        }
    }
}

// ------------- scan with 4-aligned bucket starts ----------------------------
__global__ __launch_bounds__(256) void k_scan_block(const int* __restrict__ counts,
                                                    int* __restrict__ offs,
                                                    int* __restrict__ bsum, int N) {
    __shared__ int sd[256];
    int t = threadIdx.x, b = blockIdx.x;
    int i0 = b * CHUNK + t * 4;
    int p[4];
#pragma unroll
    for (int j = 0; j < 4; ++j)
        p[j] = (i0 + j < N) ? ((counts[i0 + j] + 3) & ~3) : 0;
    int tsum = p[0] + p[1] + p[2] + p[3];
    sd[t] = tsum;
    __syncthreads();
    for (int d = 1; d < 256; d <<= 1) {
        int v = (t >= d) ? sd[t - d] : 0;
        __syncthreads();
        sd[t] += v;
        __syncthreads();
    }
    int pre = sd[t] - tsum;
#pragma unroll
    for (int j = 0; j < 4; ++j) {
        if (i0 + j < N) offs[i0 + j] = pre;
        pre += p[j];
    }
    if (t == 255) bsum[b] = sd[255];
}

__global__ void k_scan_top(const int* __restrict__ bsum, int* __restrict__ bscan, int nb) {
    int lane = threadIdx.x & 63;
    int x = (lane < nb) ? bsum[lane] : 0;
    int own = x;
    for (int d = 1; d < 64; d <<= 1) {
        int v = __shfl_up(x, d);
        if (lane >= d) x += v;
    }
    if (lane < nb) bscan[lane] = x - own;
}

__global__ __launch_bounds__(256) void k_addoff(int* __restrict__ offs,
                                                int* __restrict__ cursor,
                                                const int* __restrict__ bscan, int N) {
    int i = blockIdx.x * 256 + threadIdx.x;
    if (i < N) {
        int o = offs[i] + bscan[i >> 10];
        offs[i] = o;
        cursor[i] = o;
    }
}

// ------------- scatter: bucket by dst, alpha (fp32 x4) once per edge --------
__global__ __launch_bounds__(256) void k_scatter(const int* __restrict__ src,
                                                 const int* __restrict__ dst,
                                                 const float* __restrict__ ef,
                                                 const float* __restrict__ att,
                                                 const float* __restrict__ s_src,
                                                 const float* __restrict__ s_dst,
                                                 int* __restrict__ cursor,
                                                 int* __restrict__ s_sorted,
                                                 float* __restrict__ alphaF, int E) {
    int e = blockIdx.x * 256 + threadIdx.x;
    if (e >= E) return;
    int s = src[e], d = dst[e];
    float f = ef[e];
    int pos = atomicAdd(&cursor[d], 1);
    float4 ss = *reinterpret_cast<const float4*>(&s_src[(size_t)s * 4]);
    float4 sd = *reinterpret_cast<const float4*>(&s_dst[(size_t)d * 4]);
    const float* ssp = (const float*)&ss;
    const float* sdp = (const float*)&sd;
    float a[4];
#pragma unroll
    for (int hd = 0; hd < 4; ++hd) {
        float sc = ssp[hd] + sdp[hd] + f * att[hd * 65 + 64];
        sc = sc >= 0.f ? sc : 0.2f * sc;
        sc = fminf(fmaxf(sc, -20.f), 20.f);
        a[hd] = expf(sc);
    }
    s_sorted[pos] = s;
    *reinterpret_cast<float4*>(&alphaF[(size_t)pos * 4]) =
        make_float4(a[0], a[1], a[2], a[3]);
}

// ------------- fused: aggregate (bf16 z) + residual + LN + ELU --------------
__global__ __launch_bounds__(256) void k_agg_final(const int* __restrict__ offs,
                                                   const int* __restrict__ counts,
                                                   const int* __restrict__ s_sorted,
                                                   const float* __restrict__ alphaF,
                                                   const unsigned int* __restrict__ zb,
                                                   const float* __restrict__ z,
                                                   const float* __restrict__ g,
                                                   const float* __restrict__ bparm,
                                                   float* __restrict__ out, int N) {
    int wave = threadIdx.x >> 6, lane = threadIdx.x & 63;
    int n = blockIdx.x * 4 + wave;
    if (n >= N) return;
    const int start = offs[n], len = counts[n];
    const int hd = lane >> 4;
    const int c = lane * 2;
    const float* af = alphaF + hd;
    float ax = 0.f, ay = 0.f, da = 0.f;
    float bx = 0.f, by = 0.f, db = 0.f;
    int i = start;
    const int end = start + len;
    for (; i + 7 < end; i += 8) {
        int4 sa = *reinterpret_cast<const int4*>(&s_sorted[i]);
        int4 sb = *reinterpret_cast<const int4*>(&s_sorted[i + 4]);
        float a0 = af[(size_t)(i + 0) * 4], a1 = af[(size_t)(i + 1) * 4];
        float a2 = af[(size_t)(i + 2) * 4], a3 = af[(size_t)(i + 3) * 4];
        float a4 = af[(size_t)(i + 4) * 4], a5 = af[(size_t)(i + 5) * 4];
        float a6 = af[(size_t)(i + 6) * 4], a7 = af[(size_t)(i + 7) * 4];
        unsigned p0 = zb[(size_t)sa.x * 64 + lane];
        unsigned p1 = zb[(size_t)sa.y * 64 + lane];
        unsigned p2 = zb[(size_t)sa.z * 64 + lane];
        unsigned p3 = zb[(size_t)sa.w * 64 + lane];
        unsigned p4 = zb[(size_t)sb.x * 64 + lane];
        unsigned p5 = zb[(size_t)sb.y * 64 + lane];
        unsigned p6 = zb[(size_t)sb.z * 64 + lane];
        unsigned p7 = zb[(size_t)sb.w * 64 + lane];
        ax += __uint_as_float(p0 << 16) * a0; ay += __uint_as_float(p0 & 0xffff0000u) * a0; da += a0;
        bx += __uint_as_float(p1 << 16) * a1; by += __uint_as_float(p1 & 0xffff0000u) * a1; db += a1;
        ax += __uint_as_float(p2 << 16) * a2; ay += __uint_as_float(p2 & 0xffff0000u) * a2; da += a2;
        bx += __uint_as_float(p3 << 16) * a3; by += __uint_as_float(p3 & 0xffff0000u) * a3; db += a3;
        ax += __uint_as_float(p4 << 16) * a4; ay += __uint_as_float(p4 & 0xffff0000u) * a4; da += a4;
        bx += __uint_as_float(p5 << 16) * a5; by += __uint_as_float(p5 & 0xffff0000u) * a5; db += a5;
        ax += __uint_as_float(p6 << 16) * a6; ay += __uint_as_float(p6 & 0xffff0000u) * a6; da += a6;
        bx += __uint_as_float(p7 << 16) * a7; by += __uint_as_float(p7 & 0xffff0000u) * a7; db += a7;
    }
    for (; i + 3 < end; i += 4) {
        int4 s4 = *reinterpret_cast<const int4*>(&s_sorted[i]);
        float a0 = af[(size_t)(i + 0) * 4], a1 = af[(size_t)(i + 1) * 4];
        float a2 = af[(size_t)(i + 2) * 4], a3 = af[(size_t)(i + 3) * 4];
        unsigned p0 = zb[(size_t)s4.x * 64 + lane];
        unsigned p1 = zb[(size_t)s4.y * 64 + lane];
        unsigned p2 = zb[(size_t)s4.z * 64 + lane];
        unsigned p3 = zb[(size_t)s4.w * 64 + lane];
        ax += __uint_as_float(p0 << 16) * a0; ay += __uint_as_float(p0 & 0xffff0000u) * a0; da += a0;
        bx += __uint_as_float(p1 << 16) * a1; by += __uint_as_float(p1 & 0xffff0000u) * a1; db += a1;
        ax += __uint_as_float(p2 << 16) * a2; ay += __uint_as_float(p2 & 0xffff0000u) * a2; da += a2;
        bx += __uint_as_float(p3 << 16) * a3; by += __uint_as_float(p3 & 0xffff0000u) * a3; db += a3;
    }
    for (; i < end; ++i) {
        int s0 = s_sorted[i];
        float a0 = af[(size_t)i * 4];
        unsigned p0 = zb[(size_t)s0 * 64 + lane];
        ax += __uint_as_float(p0 << 16) * a0;
        ay += __uint_as_float(p0 & 0xffff0000u) * a0;
        da += a0;
    }

    float inv = 1.f / (da + db + 1e-6f);
    float2 zv = *reinterpret_cast<const float2*>(&z[(size_t)n * 128 + c]);
    float x0 = (ax + bx) * inv + zv.x;
    float x1 = (ay + by) * inv + zv.y;
    float s = x0 + x1;
    for (int off = 32; off; off >>= 1) s += __shfl_xor(s, off);
    float mu = s * (1.f / 128.f);
    float d0 = x0 - mu, d1 = x1 - mu;
    float q = d0 * d0 + d1 * d1;
    for (int off = 32; off; off >>= 1) q += __shfl_xor(q, off);
    float rstd = rsqrtf(q * (1.f / 128.f) + 1e-5f);
    float2 gg = *reinterpret_cast<const float2*>(&g[c]);
    float2 bb = *reinterpret_cast<const float2*>(&bparm[c]);
    float y0 = d0 * rstd * gg.x + bb.x;
    float y1 = d1 * rstd * gg.y + bb.y;
    y0 = y0 > 0.f ? y0 : expf(y0) - 1.f;
    y1 = y1 > 0.f ? y1 : expf(y1) - 1.f;
    *reinterpret_cast<float2*>(&out[(size_t)n * 128 + c]) = make_float2(y0, y1);
}

extern "C" void kernel_launch(void* const* d_in, const int* in_sizes, int n_in,
                              void* d_out, int out_size, void* d_ws, size_t ws_size,
                              hipStream_t stream) {
    const float* h   = (const float*)d_in[0];
    const int*   ei  = (const int*)d_in[1];
    const float* ef  = (const float*)d_in[2];
    const float* Ww  = (const float*)d_in[3];
    const float* Wb  = (const float*)d_in[4];
    const float* att = (const float*)d_in[5];
    const float* lng = (const float*)d_in[6];
    const float* lnb = (const float*)d_in[7];
    float* out = (float*)d_out;

    const int N = in_sizes[0] / 128;   // 50000
    const int E = in_sizes[1] / 2;     // 800000
    const int* src = ei;
    const int* dst = ei + E;
    const int nb = (N + CHUNK - 1) / CHUNK;
    const int sortedCap = E + 3 * N + 64;

    char* ws = (char*)d_ws;
    float*          z        = (float*)ws;          ws += (size_t)N * 128 * 4;
    unsigned short* zb16     = (unsigned short*)ws; ws += (size_t)N * 128 * 2;
    float*          s_src    = (float*)ws;          ws += (size_t)N * 4 * 4;
    float*          s_dst    = (float*)ws;          ws += (size_t)N * 4 * 4;
    int*            counts   = (int*)ws;            ws += (size_t)N * 4;
    int*            offs     = (int*)ws;            ws += (size_t)N * 4;
    int*            cursor   = (int*)ws;            ws += (size_t)N * 4;
    int*            bsum     = (int*)ws;            ws += (size_t)64 * 4;
    int*            bscan    = (int*)ws;            ws += (size_t)64 * 4;
    float*          wsd      = (float*)ws;          ws += (size_t)1032 * 4;
    int*            s_sorted = (int*)ws;            ws += (size_t)sortedCap * 4;
    float*          alphaF   = (float*)ws;          ws += (size_t)sortedCap * 16;

    hipMemsetAsync(counts, 0, (size_t)N * 4, stream);
    k_prep<<<1, 256, 0, stream>>>(Ww, Wb, att, wsd);

    const int gemmBlocks  = (N + 63) / 64;           // 782
    const int scoreBlocks = (N * 8 + 255) / 256;     // 1563
    const int histBlocks  = (E + 1023) / 1024;       // 782
    k_mega<<<gemmBlocks + scoreBlocks + histBlocks, 256, 0, stream>>>(
        h, Ww, Wb, wsd, dst, counts, z, zb16, s_src, s_dst,
        N, E, gemmBlocks, scoreBlocks);
    k_scan_block<<<nb, 256, 0, stream>>>(counts, offs, bsum, N);
    k_scan_top<<<1, 64, 0, stream>>>(bsum, bscan, nb);
    k_addoff<<<(N + 255) / 256, 256, 0, stream>>>(offs, cursor, bscan, N);
    k_scatter<<<(E + 255) / 256, 256, 0, stream>>>(src, dst, ef, att, s_src, s_dst, cursor, s_sorted, alphaF, E);
    k_agg_final<<<(N + 3) / 4, 256, 0, stream>>>(offs, counts, s_sorted, alphaF,
                                                 (const unsigned int*)zb16, z, lng, lnb, out, N);
}

// Round 8
// 152.049 us; speedup vs baseline: 1.0892x; 1.0892x over previous
//
#include <hip/hip_runtime.h>
#include <hip/hip_bf16.h>
#include <math.h>

#define CHUNK 1024

typedef __attribute__((ext_vector_type(8))) short bf16x8;
typedef __attribute__((ext_vector_type(4))) float f32x4;

__device__ __forceinline__ unsigned short f2bf(float f) {
    unsigned u = __float_as_uint(f);
    unsigned r = ((u >> 16) & 1u) + 0x7fffu;   // RNE
    return (unsigned short)((u + r) >> 16);
}

// ---- prep: W -> bf16 in MFMA B-fragment order; zero counts ------------------
// granule gi = kg*128 + row (kg in [0,16), row in [0,128)), elems e in [0,8):
//   k = (kg>>2)*32 + (e>>2)*16 + (kg&3)*4 + (e&3)
__global__ __launch_bounds__(256) void k_prep(const float* __restrict__ W,
                                              unsigned short* __restrict__ Wb16,
                                              int* __restrict__ counts, int N) {
    const int t = threadIdx.x;
    const int bid = blockIdx.x;
    if (bid == 0) {
#pragma unroll
        for (int q = 0; q < 8; ++q) {
            int gi = q * 256 + t;
            int kg = gi >> 7, row = gi & 127;
            int kbase = (kg >> 2) * 32 + (kg & 3) * 4;
            unsigned pk[4];
#pragma unroll
            for (int p = 0; p < 4; ++p) {   // elem pairs (2p, 2p+1)
                int e0 = 2 * p, e1 = 2 * p + 1;
                float v0 = W[(size_t)row * 128 + kbase + (e0 >> 2) * 16 + (e0 & 3)];
                float v1 = W[(size_t)row * 128 + kbase + (e1 >> 2) * 16 + (e1 & 3)];
                pk[p] = ((unsigned)f2bf(v1) << 16) | f2bf(v0);
            }
            *reinterpret_cast<uint4*>(&Wb16[(size_t)gi * 8]) =
                make_uint4(pk[0], pk[1], pk[2], pk[3]);
        }
    } else {
        int i = ((bid - 1) * 256 + t) * 4;
        if (i < N) *reinterpret_cast<int4*>(&counts[i]) = make_int4(0, 0, 0, 0);
    }
}

// ---- mega: MFMA GEMM (bf16 in / fp32 acc) + in-register scores + hist ------
__global__ __launch_bounds__(256) void k_mega(
        const float* __restrict__ h, const unsigned short* __restrict__ Wb16,
        const float* __restrict__ bias, const float* __restrict__ att,
        const int* __restrict__ dstI, int* __restrict__ counts,
        unsigned short* __restrict__ zb16,
        float* __restrict__ s_src, float* __restrict__ s_dst,
        int N, int E, int gemmBlocks) {
    __shared__ short hS[16 * 64 * 8];    // 16 KB: h tile in A-fragment granules
    const int t = threadIdx.x;
    const int bid = blockIdx.x;

    if (bid >= gemmBlocks) {             // ---- histogram (4 edges/thread) ----
        int base = (bid - gemmBlocks) * 1024 + t;
#pragma unroll
        for (int q = 0; q < 4; ++q) {
            int e = base + q * 256;
            if (e < E) atomicAdd(&counts[dstI[e]], 1);
        }
        return;
    }

    // ---- GEMM block: 64 nodes x 128 outs ----
    const int n0 = bid * 64;
    // stage h (64 x 128 fp32 -> bf16 fragment granules, row-XOR swizzle)
#pragma unroll
    for (int q = 0; q < 8; ++q) {
        int f = q * 256 + t;
        int node = f >> 5;
        int k4 = (f & 31) * 4;
        int ks = k4 >> 5, rr = k4 & 31;
        int half = rr >> 4, g = (rr & 15) >> 2;
        int kg = ks * 4 + g;
        int slot = kg * 64 + (node ^ (kg & 7));
        int hn = n0 + node; if (hn > N - 1) hn = N - 1;
        float4 v = *reinterpret_cast<const float4*>(&h[(size_t)hn * 128 + k4]);
        uint2 pk = make_uint2(((unsigned)f2bf(v.y) << 16) | f2bf(v.x),
                              ((unsigned)f2bf(v.w) << 16) | f2bf(v.z));
        *reinterpret_cast<uint2*>(&hS[slot * 8 + half * 4]) = pk;
    }
    __syncthreads();

    const int wv = t >> 6, l = t & 63;
    const int la = l & 15, lb = l >> 4;
    const int nbase = wv * 16;

    bf16x8 afr[4];
#pragma unroll
    for (int ks = 0; ks < 4; ++ks) {
        int kg = ks * 4 + lb;
        int slot = kg * 64 + ((nbase + la) ^ (kg & 7));
        afr[ks] = *reinterpret_cast<const bf16x8*>(&hS[slot * 8]);
    }

    float sS[4][4], sD[4][4];
#pragma unroll
    for (int r = 0; r < 4; ++r)
#pragma unroll
        for (int hd = 0; hd < 4; ++hd) { sS[r][hd] = 0.f; sD[r][hd] = 0.f; }

#pragma unroll
    for (int ot = 0; ot < 8; ++ot) {
        f32x4 acc = {0.f, 0.f, 0.f, 0.f};
#pragma unroll
        for (int ks = 0; ks < 4; ++ks) {
            int gi = (ks * 4 + lb) * 128 + ot * 16 + la;
            bf16x8 bfr = *reinterpret_cast<const bf16x8*>(&Wb16[(size_t)gi * 8]);
            acc = __builtin_amdgcn_mfma_f32_16x16x32_bf16(afr[ks], bfr, acc, 0, 0, 0);
        }
        const int col = ot * 16 + la;
        const int hd = ot >> 1;                       // head of this col
        float bv = bias[col];
        float aS = att[hd * 65 + (ot & 1) * 16 + la];
        float aD = att[hd * 65 + 32 + (ot & 1) * 16 + la];
#pragma unroll
        for (int r = 0; r < 4; ++r) {
            int node = n0 + nbase + lb * 4 + r;
            float v = acc[r] + bv;
            sS[r][hd] += v * aS;
            sD[r][hd] += v * aD;
            if (node < N) zb16[(size_t)node * 128 + col] = f2bf(v);
        }
    }

    // butterfly-reduce scores over the 16-lane la group
#pragma unroll
    for (int r = 0; r < 4; ++r)
#pragma unroll
        for (int hd = 0; hd < 4; ++hd) {
#pragma unroll
            for (int off = 1; off < 16; off <<= 1) {
                sS[r][hd] += __shfl_xor(sS[r][hd], off);
                sD[r][hd] += __shfl_xor(sD[r][hd], off);
            }
        }
    if (la < 4) {
#pragma unroll
        for (int r = 0; r < 4; ++r) {
            int node = n0 + nbase + lb * 4 + r;
            if (node < N) {
                float vS = (la == 0) ? sS[r][0] : (la == 1) ? sS[r][1]
                         : (la == 2) ? sS[r][2] : sS[r][3];
                float vD = (la == 0) ? sD[r][0] : (la == 1) ? sD[r][1]
                         : (la == 2) ? sD[r][2] : sD[r][3];
                s_src[(size_t)node * 4 + la] = vS;
                s_dst[(size_t)node * 4 + la] = vD;
            }
        }
    }
}

// ------------- scan with 4-aligned bucket starts ----------------------------
__global__ __launch_bounds__(256) void k_scan_block(const int* __restrict__ counts,
                                                    int* __restrict__ offs,
                                                    int* __restrict__ bsum, int N) {
    __shared__ int sd[256];
    int t = threadIdx.x, b = blockIdx.x;
    int i0 = b * CHUNK + t * 4;
    int p[4];
#pragma unroll
    for (int j = 0; j < 4; ++j)
        p[j] = (i0 + j < N) ? ((counts[i0 + j] + 3) & ~3) : 0;
    int tsum = p[0] + p[1] + p[2] + p[3];
    sd[t] = tsum;
    __syncthreads();
    for (int d = 1; d < 256; d <<= 1) {
        int v = (t >= d) ? sd[t - d] : 0;
        __syncthreads();
        sd[t] += v;
        __syncthreads();
    }
    int pre = sd[t] - tsum;
#pragma unroll
    for (int j = 0; j < 4; ++j) {
        if (i0 + j < N) offs[i0 + j] = pre;
        pre += p[j];
    }
    if (t == 255) bsum[b] = sd[255];
}

// addoff with inline top-scan (nb <= 64)
__global__ __launch_bounds__(256) void k_addoff(int* __restrict__ offs,
                                                int* __restrict__ cursor,
                                                const int* __restrict__ bsum,
                                                int N, int nb) {
    __shared__ int base_s;
    int t = threadIdx.x;
    int i = blockIdx.x * 256 + t;
    int chunk = (blockIdx.x * 256) >> 10;
    if (t < 64) {
        int v = (t < chunk && t < nb) ? bsum[t] : 0;
#pragma unroll
        for (int off = 1; off < 64; off <<= 1) v += __shfl_xor(v, off);
        if (t == 0) base_s = v;
    }
    __syncthreads();
    if (i < N) {
        int o = offs[i] + base_s;
        offs[i] = o;
        cursor[i] = o;
    }
}

// ------------- scatter: bucket by dst, alpha (fp32 x4) once per edge --------
__global__ __launch_bounds__(256) void k_scatter(const int* __restrict__ src,
                                                 const int* __restrict__ dst,
                                                 const float* __restrict__ ef,
                                                 const float* __restrict__ att,
                                                 const float* __restrict__ s_src,
                                                 const float* __restrict__ s_dst,
                                                 int* __restrict__ cursor,
                                                 int* __restrict__ s_sorted,
                                                 float* __restrict__ alphaF, int E) {
    int e = blockIdx.x * 256 + threadIdx.x;
    if (e >= E) return;
    int s = src[e], d = dst[e];
    float f = ef[e];
    int pos = atomicAdd(&cursor[d], 1);
    float4 ss = *reinterpret_cast<const float4*>(&s_src[(size_t)s * 4]);
    float4 sd = *reinterpret_cast<const float4*>(&s_dst[(size_t)d * 4]);
    const float* ssp = (const float*)&ss;
    const float* sdp = (const float*)&sd;
    float a[4];
#pragma unroll
    for (int hd = 0; hd < 4; ++hd) {
        float sc = ssp[hd] + sdp[hd] + f * att[hd * 65 + 64];
        sc = sc >= 0.f ? sc : 0.2f * sc;
        sc = fminf(fmaxf(sc, -20.f), 20.f);
        a[hd] = expf(sc);
    }
    s_sorted[pos] = s;
    *reinterpret_cast<float4*>(&alphaF[(size_t)pos * 4]) =
        make_float4(a[0], a[1], a[2], a[3]);
}

// ------------- fused: aggregate (bf16 z) + residual + LN + ELU --------------
__global__ __launch_bounds__(256) void k_agg_final(const int* __restrict__ offs,
                                                   const int* __restrict__ counts,
                                                   const int* __restrict__ s_sorted,
                                                   const float* __restrict__ alphaF,
                                                   const unsigned int* __restrict__ zb,
                                                   const float* __restrict__ g,
                                                   const float* __restrict__ bparm,
                                                   float* __restrict__ out, int N) {
    int wave = threadIdx.x >> 6, lane = threadIdx.x & 63;
    int n = blockIdx.x * 4 + wave;
    if (n >= N) return;
    const int start = offs[n], len = counts[n];
    const int hd = lane >> 4;
    const int c = lane * 2;
    const float* af = alphaF + hd;
    float ax = 0.f, ay = 0.f, da = 0.f;
    float bx = 0.f, by = 0.f, db = 0.f;
    int i = start;
    const int end = start + len;
    for (; i + 7 < end; i += 8) {
        int4 sa = *reinterpret_cast<const int4*>(&s_sorted[i]);
        int4 sb = *reinterpret_cast<const int4*>(&s_sorted[i + 4]);
        float a0 = af[(size_t)(i + 0) * 4], a1 = af[(size_t)(i + 1) * 4];
        float a2 = af[(size_t)(i + 2) * 4], a3 = af[(size_t)(i + 3) * 4];
        float a4 = af[(size_t)(i + 4) * 4], a5 = af[(size_t)(i + 5) * 4];
        float a6 = af[(size_t)(i + 6) * 4], a7 = af[(size_t)(i + 7) * 4];
        unsigned p0 = zb[(size_t)sa.x * 64 + lane];
        unsigned p1 = zb[(size_t)sa.y * 64 + lane];
        unsigned p2 = zb[(size_t)sa.z * 64 + lane];
        unsigned p3 = zb[(size_t)sa.w * 64 + lane];
        unsigned p4 = zb[(size_t)sb.x * 64 + lane];
        unsigned p5 = zb[(size_t)sb.y * 64 + lane];
        unsigned p6 = zb[(size_t)sb.z * 64 + lane];
        unsigned p7 = zb[(size_t)sb.w * 64 + lane];
        ax += __uint_as_float(p0 << 16) * a0; ay += __uint_as_float(p0 & 0xffff0000u) * a0; da += a0;
        bx += __uint_as_float(p1 << 16) * a1; by += __uint_as_float(p1 & 0xffff0000u) * a1; db += a1;
        ax += __uint_as_float(p2 << 16) * a2; ay += __uint_as_float(p2 & 0xffff0000u) * a2; da += a2;
        bx += __uint_as_float(p3 << 16) * a3; by += __uint_as_float(p3 & 0xffff0000u) * a3; db += a3;
        ax += __uint_as_float(p4 << 16) * a4; ay += __uint_as_float(p4 & 0xffff0000u) * a4; da += a4;
        bx += __uint_as_float(p5 << 16) * a5; by += __uint_as_float(p5 & 0xffff0000u) * a5; db += a5;
        ax += __uint_as_float(p6 << 16) * a6; ay += __uint_as_float(p6 & 0xffff0000u) * a6; da += a6;
        bx += __uint_as_float(p7 << 16) * a7; by += __uint_as_float(p7 & 0xffff0000u) * a7; db += a7;
    }
    for (; i + 3 < end; i += 4) {
        int4 s4 = *reinterpret_cast<const int4*>(&s_sorted[i]);
        float a0 = af[(size_t)(i + 0) * 4], a1 = af[(size_t)(i + 1) * 4];
        float a2 = af[(size_t)(i + 2) * 4], a3 = af[(size_t)(i + 3) * 4];
        unsigned p0 = zb[(size_t)s4.x * 64 + lane];
        unsigned p1 = zb[(size_t)s4.y * 64 + lane];
        unsigned p2 = zb[(size_t)s4.z * 64 + lane];
        unsigned p3 = zb[(size_t)s4.w * 64 + lane];
        ax += __uint_as_float(p0 << 16) * a0; ay += __uint_as_float(p0 & 0xffff0000u) * a0; da += a0;
        bx += __uint_as_float(p1 << 16) * a1; by += __uint_as_float(p1 & 0xffff0000u) * a1; db += a1;
        ax += __uint_as_float(p2 << 16) * a2; ay += __uint_as_float(p2 & 0xffff0000u) * a2; da += a2;
        bx += __uint_as_float(p3 << 16) * a3; by += __uint_as_float(p3 & 0xffff0000u) * a3; db += a3;
    }
    for (; i < end; ++i) {
        int s0 = s_sorted[i];
        float a0 = af[(size_t)i * 4];
        unsigned p0 = zb[(size_t)s0 * 64 + lane];
        ax += __uint_as_float(p0 << 16) * a0;
        ay += __uint_as_float(p0 & 0xffff0000u) * a0;
        da += a0;
    }

    float inv = 1.f / (da + db + 1e-6f);
    unsigned pz = zb[(size_t)n * 64 + lane];
    float x0 = (ax + bx) * inv + __uint_as_float(pz << 16);
    float x1 = (ay + by) * inv + __uint_as_float(pz & 0xffff0000u);
    float s = x0 + x1;
    for (int off = 32; off; off >>= 1) s += __shfl_xor(s, off);
    float mu = s * (1.f / 128.f);
    float d0 = x0 - mu, d1 = x1 - mu;
    float q = d0 * d0 + d1 * d1;
    for (int off = 32; off; off >>= 1) q += __shfl_xor(q, off);
    float rstd = rsqrtf(q * (1.f / 128.f) + 1e-5f);
    float2 gg = *reinterpret_cast<const float2*>(&g[c]);
    float2 bb = *reinterpret_cast<const float2*>(&bparm[c]);
    float y0 = d0 * rstd * gg.x + bb.x;
    float y1 = d1 * rstd * gg.y + bb.y;
    y0 = y0 > 0.f ? y0 : expf(y0) - 1.f;
    y1 = y1 > 0.f ? y1 : expf(y1) - 1.f;
    *reinterpret_cast<float2*>(&out[(size_t)n * 128 + c]) = make_float2(y0, y1);
}

extern "C" void kernel_launch(void* const* d_in, const int* in_sizes, int n_in,
                              void* d_out, int out_size, void* d_ws, size_t ws_size,
                              hipStream_t stream) {
    const float* h   = (const float*)d_in[0];
    const int*   ei  = (const int*)d_in[1];
    const float* ef  = (const float*)d_in[2];
    const float* Ww  = (const float*)d_in[3];
    const float* Wb  = (const float*)d_in[4];
    const float* att = (const float*)d_in[5];
    const float* lng = (const float*)d_in[6];
    const float* lnb = (const float*)d_in[7];
    float* out = (float*)d_out;

    const int N = in_sizes[0] / 128;   // 50000
    const int E = in_sizes[1] / 2;     // 800000
    const int* src = ei;
    const int* dst = ei + E;
    const int nb = (N + CHUNK - 1) / CHUNK;   // 49 (<=64 required)
    const int sortedCap = E + 3 * N + 64;

    char* ws = (char*)d_ws;
    unsigned short* zb16     = (unsigned short*)ws; ws += (size_t)N * 128 * 2;
    unsigned short* Wb16     = (unsigned short*)ws; ws += (size_t)128 * 128 * 2;
    float*          s_src    = (float*)ws;          ws += (size_t)N * 4 * 4;
    float*          s_dst    = (float*)ws;          ws += (size_t)N * 4 * 4;
    int*            counts   = (int*)ws;            ws += (size_t)N * 4;
    int*            offs     = (int*)ws;            ws += (size_t)N * 4;
    int*            cursor   = (int*)ws;            ws += (size_t)N * 4;
    int*            bsum     = (int*)ws;            ws += (size_t)64 * 4;
    int*            s_sorted = (int*)ws;            ws += (size_t)sortedCap * 4;
    float*          alphaF   = (float*)ws;          ws += (size_t)sortedCap * 16;

    const int zeroBlocks = (N + 1023) / 1024;        // 49
    k_prep<<<1 + zeroBlocks, 256, 0, stream>>>(Ww, Wb16, counts, N);

    const int gemmBlocks = (N + 63) / 64;            // 782
    const int histBlocks = (E + 1023) / 1024;        // 782
    k_mega<<<gemmBlocks + histBlocks, 256, 0, stream>>>(
        h, Wb16, Wb, att, dst, counts, zb16, s_src, s_dst, N, E, gemmBlocks);
    k_scan_block<<<nb, 256, 0, stream>>>(counts, offs, bsum, N);
    k_addoff<<<(N + 255) / 256, 256, 0, stream>>>(offs, cursor, bsum, N, nb);
    k_scatter<<<(E + 255) / 256, 256, 0, stream>>>(src, dst, ef, att, s_src, s_dst, cursor, s_sorted, alphaF, E);
    k_agg_final<<<(N + 3) / 4, 256, 0, stream>>>(offs, counts, s_sorted, alphaF,
                                                 (const unsigned int*)zb16, lng, lnb, out, N);
}